// Round 2
// baseline (285.736 us; speedup 1.0000x reference)
//
#include <hip/hip_runtime.h>

typedef _Float16 f16;
typedef _Float16 f16x4 __attribute__((ext_vector_type(4)));
typedef _Float16 f16x8 __attribute__((ext_vector_type(8)));
typedef float f32x4 __attribute__((ext_vector_type(4)));

// A[px][k]: 16 px rows x 2048 f16 (4096 B per row). 16-B chunks XOR-swizzled
// by px (4 bits): byte = px*4096 + ((k>>3)^(px&15))*16 + (k&7)*2.
static __device__ inline char* a_addr(char* Abase, int px, int k) {
    return Abase + px * 4096 + ((((k >> 3) ^ (px & 15)) << 4) | ((k & 7) << 1));
}

// ---------------------------------------------------------------------------
// k_setup: grid 65 x 1024.
// block 0:      full query path for all 8 b (deep-pipelined float4 streams)
// blocks 1..64: 4 M-role subtiles each: M_e = Wv_e @ w_out_e -> mtp
// ---------------------------------------------------------------------------
__launch_bounds__(1024)
__global__ void k_setup(const int* __restrict__ q, const float* __restrict__ emb,
                        const float* __restrict__ w1, const float* __restrict__ b1,
                        const float* __restrict__ w2, const float* __restrict__ b2,
                        const float* __restrict__ w_kv, const float* __restrict__ w_out,
                        const float* __restrict__ rms_w,
                        f16* __restrict__ qkw, f16* __restrict__ mtp) {
    int blk = blockIdx.x;
    int t = threadIdx.x;

    if (blk == 0) {
        // ---- query path: all 8 b in one block ----
        __shared__ float qeL[8][256];
        __shared__ float x1L[8][512];
        __shared__ float qhL[8][512];
        {
            int bb = t >> 8, c = t & 255;
            qeL[bb][c]     = emb[(size_t)q[bb] * 256 + c];
            qeL[bb + 4][c] = emb[(size_t)q[bb + 4] * 256 + c];
        }
        __syncthreads();
        {   // x1[b][h] = silu(qe[b] @ w1 + b1): thread = (b, 4-h group)
            int bb = t >> 7, hq = t & 127;
            float4 bv = *(const float4*)(b1 + hq * 4);
            f32x4 acc = {bv.x, bv.y, bv.z, bv.w};
#pragma unroll 8
            for (int c = 0; c < 256; ++c) {
                float4 wr = *(const float4*)(w1 + (size_t)c * 512 + hq * 4);
                float qv = qeL[bb][c];
                acc[0] += qv * wr.x; acc[1] += qv * wr.y;
                acc[2] += qv * wr.z; acc[3] += qv * wr.w;
            }
#pragma unroll
            for (int j = 0; j < 4; ++j) {
                float a = acc[j];
                x1L[bb][hq * 4 + j] = a / (1.f + __expf(-a));
            }
        }
        __syncthreads();
        {   // qh[b][o] = x1[b] @ w2 + b2: thread = (b, 4-o group)
            int bb = t >> 7, oq = t & 127;
            float4 bv = *(const float4*)(b2 + oq * 4);
            f32x4 acc = {bv.x, bv.y, bv.z, bv.w};
#pragma unroll 8
            for (int k = 0; k < 512; ++k) {
                float4 wr = *(const float4*)(w2 + (size_t)k * 512 + oq * 4);
                float xv = x1L[bb][k];
                acc[0] += xv * wr.x; acc[1] += xv * wr.y;
                acc[2] += xv * wr.z; acc[3] += xv * wr.w;
            }
#pragma unroll
            for (int j = 0; j < 4; ++j) qhL[bb][oq * 4 + j] = acc[j];
        }
        __syncthreads();
        {   // qkw[b,e,c] = rms_w[c] * sum_d qh[b][e*64+d]*w_kv[c][e*128+d]
            int c = t & 255;
            float rw = rms_w[c];
#pragma unroll
            for (int e2 = 0; e2 < 2; ++e2) {
                int e = (t >> 8) * 2 + e2;
                const float* col = w_kv + (size_t)c * 1024 + e * 128;   // K-half
                float acc[8] = {0.f, 0.f, 0.f, 0.f, 0.f, 0.f, 0.f, 0.f};
#pragma unroll 4
                for (int dq = 0; dq < 16; ++dq) {
                    float4 wv4 = *(const float4*)(col + dq * 4);
#pragma unroll
                    for (int bb = 0; bb < 8; ++bb) {
                        const float* qb = &qhL[bb][e * 64 + dq * 4];
                        acc[bb] += wv4.x * qb[0] + wv4.y * qb[1]
                                 + wv4.z * qb[2] + wv4.w * qb[3];
                    }
                }
#pragma unroll
                for (int bb = 0; bb < 8; ++bb)
                    qkw[(bb * 8 + e) * 256 + c] = (f16)(acc[bb] * rw);
            }
        }
    } else {
        // ---- M role: 4 subtiles of (e, 8-c tile) per block ----
        __shared__ float wv[4][64][8];
        int sub = t >> 8, st = t & 255;
        int mb = (blk - 1) * 4 + sub;
        int e = mb >> 5, c0 = (mb & 31) * 8;
        int o = st;
        // prefetch w_out column (64 rows) into regs: one latency, not 16
        float wo[64];
#pragma unroll
        for (int d = 0; d < 64; ++d) wo[d] = w_out[(size_t)(e * 64 + d) * 256 + o];
        {
            int d = st & 63, cc = st >> 6;
            wv[sub][d][cc]     = w_kv[(size_t)(c0 + cc) * 1024 + e * 128 + 64 + d];
            wv[sub][d][cc + 4] = w_kv[(size_t)(c0 + cc + 4) * 1024 + e * 128 + 64 + d];
        }
        __syncthreads();
        float acc[8];
#pragma unroll
        for (int c = 0; c < 8; ++c) acc[c] = 0.f;
#pragma unroll 8
        for (int d = 0; d < 64; ++d) {
            float w = wo[d];
            float4 wa = *(const float4*)&wv[sub][d][0];
            float4 wb = *(const float4*)&wv[sub][d][4];
            acc[0] += wa.x * w; acc[1] += wa.y * w; acc[2] += wa.z * w; acc[3] += wa.w * w;
            acc[4] += wb.x * w; acc[5] += wb.y * w; acc[6] += wb.z * w; acc[7] += wb.w * w;
        }
        f16x8 ov;
#pragma unroll
        for (int c = 0; c < 8; ++c) ov[c] = (f16)(acc[c] * rms_w[c0 + c]);
        *(f16x8*)(mtp + ((size_t)((e * 256 + c0) >> 3) * 256 + o) * 8) = ov;
    }
}

// ---------------------------------------------------------------------------
// helpers for k_attn (operate on one 16-px tile in LDS buffer A)
// ---------------------------------------------------------------------------
static __device__ inline void dots_rinv(char* A, const f16* qkw_b,
                                        float (*dotsP)[8][16], float (*wred)[16],
                                        float (*rinvL)[9],
                                        int t, int w, int m16, int quad) {
    if (w < 8) {                       // dots via MFMA: wave w -> n = w
        int n = w;
        f32x4 d0 = {0.f, 0.f, 0.f, 0.f};
        const f16* qrow = qkw_b + (m16 & 7) * 256;
#pragma unroll
        for (int ks = 0; ks < 8; ++ks) {
            f16x8 a0 = *(const f16x8*)a_addr(A, m16, n * 256 + ks * 32 + quad * 8);
            f16x8 bq = *(const f16x8*)(qrow + ks * 32 + quad * 8);
            d0 = __builtin_amdgcn_mfma_f32_16x16x32_f16(a0, bq, d0, 0, 0, 0);
        }
        if (m16 < 8) {                 // D: col=m16=e, row=quad*4+r=px
#pragma unroll
            for (int r = 0; r < 4; ++r) dotsP[n][m16][quad * 4 + r] = d0[r];
        }
    } else if (w < 10) {               // rinv: 128 threads -> (px, n)
        int i = t - 512;
        int p = i & 15, n = i >> 4;
        float ss = wred[2 * n][p] + wred[2 * n + 1][p];
        rinvL[p][n] = rsqrtf(ss * (1.f / 256.f) + 1e-6f);
    }
}

static __device__ inline void blend(char* A, float (*dotsP)[8][16],
                                    float (*rinvL)[9], int t) {
    int bpx = t & 15;
    int cw = t >> 4;                   // 0..63, 4-channel window
    float rinv[8];
#pragma unroll
    for (int n = 0; n < 8; ++n) rinv[n] = rinvL[bpx][n];
    f16x4 cv[8];
#pragma unroll
    for (int n = 0; n < 8; ++n)
        cv[n] = *(const f16x4*)a_addr(A, bpx, n * 256 + cw * 4);
#pragma unroll
    for (int e = 0; e < 8; ++e) {
        float l[8];
#pragma unroll
        for (int n = 0; n < 8; ++n) l[n] = dotsP[n][e][bpx] * rinv[n] * 0.125f;
        float mx = l[0];
#pragma unroll
        for (int n = 1; n < 8; ++n) mx = fmaxf(mx, l[n]);
        float s = 0.f;
#pragma unroll
        for (int n = 0; n < 8; ++n) { l[n] = __expf(l[n] - mx); s += l[n]; }
        float inv = 1.f / s;
        f16x4 r = {};
#pragma unroll
        for (int n = 0; n < 8; ++n) {
            f16 an = (f16)(l[n] * inv * rinv[n]);
#pragma unroll
            for (int j = 0; j < 4; ++j) r[j] += cv[n][j] * an;   // v_pk_fma_f16
        }
        *(f16x4*)a_addr(A, bpx, e * 256 + cw * 4) = r;
    }
}

// ---------------------------------------------------------------------------
// k_attn v3: 1024 threads, TWO 16-px tiles per block, grid 256, 1 block/CU.
// Both tiles' global loads issued up-front (register-staged); tile1's flight
// hides under tile0's dots/blend. GEMMs fused: one mtp B-fragment feeds both
// tiles' MFMAs -> B L2-traffic halved (256 MiB total, ~7.8 us/CU floor).
// ---------------------------------------------------------------------------
__launch_bounds__(1024, 4)
__global__ void k_attn(const float* __restrict__ cin, const f16* __restrict__ qkw,
                       const f16* __restrict__ mtp, const float* __restrict__ b_out,
                       float* __restrict__ out) {
    int blk = blockIdx.x;
    int b = blk & 7;                  // XCD-local c[b] slab
    int hw0 = (blk >> 3) * 32;        // tile0 at hw0, tile1 at hw0+16
    int t = threadIdx.x;
    int lane = t & 63, w = t >> 6;    // w 0..15
    int m16 = lane & 15, quad = lane >> 4;

    __shared__ char A0[16 * 4096];    // 64 KiB swizzled f16 [16px][2048k]
    __shared__ char A1[16 * 4096];    // 64 KiB
    __shared__ float dotsP[8][8][16];
    __shared__ float wred[16][16];
    __shared__ float rinvL[16][9];

    // ---- issue BOTH tiles' loads; stage tile0 ----
    int px = m16;
    int cb = (w << 2) | quad;         // 0..63: rows cb*32..cb*32+31
    const float* src0 = cin + ((size_t)b * 2048 + (size_t)cb * 32) * 1024 + hw0 + px;
    const float* src1 = src0 + 16;

    float v0[32], v1[32];
#pragma unroll
    for (int j = 0; j < 32; ++j) v0[j] = src0[(size_t)j << 10];
    float ss0 = 0.f;
    {   // consume first 8 to keep VMEM FIFO <= 56 outstanding
        f16x8 h;
#pragma unroll
        for (int j = 0; j < 8; ++j) { float x = v0[j]; ss0 += x * x; h[j] = (f16)x; }
        *(f16x8*)a_addr(A0, px, cb * 32) = h;
    }
#pragma unroll
    for (int j = 0; j < 32; ++j) v1[j] = src1[(size_t)j << 10];
#pragma unroll
    for (int g = 1; g < 4; ++g) {
        f16x8 h;
#pragma unroll
        for (int j = 0; j < 8; ++j) { float x = v0[g * 8 + j]; ss0 += x * x; h[j] = (f16)x; }
        *(f16x8*)a_addr(A0, px, cb * 32 + g * 8) = h;
    }
    ss0 += __shfl_xor(ss0, 16);
    ss0 += __shfl_xor(ss0, 32);
    if (lane < 16) wred[w][lane] = ss0;
    __syncthreads();

    dots_rinv(A0, qkw + (size_t)b * 2048, dotsP, wred, rinvL, t, w, m16, quad);
    __syncthreads();
    blend(A0, dotsP, rinvL, t);
    __syncthreads();

    // ---- stage tile1 (v1 regs: flight was hidden under dots0/blend0) ----
    float ss1 = 0.f;
#pragma unroll
    for (int g = 0; g < 4; ++g) {
        f16x8 h;
#pragma unroll
        for (int j = 0; j < 8; ++j) { float x = v1[g * 8 + j]; ss1 += x * x; h[j] = (f16)x; }
        *(f16x8*)a_addr(A1, px, cb * 32 + g * 8) = h;
    }
    ss1 += __shfl_xor(ss1, 16);
    ss1 += __shfl_xor(ss1, 32);
    if (lane < 16) wred[w][lane] = ss1;
    __syncthreads();

    dots_rinv(A1, qkw + (size_t)b * 2048, dotsP, wred, rinvL, t, w, m16, quad);
    __syncthreads();
    blend(A1, dotsP, rinvL, t);
    __syncthreads();

    // ---- fused GEMM: one B-fragment -> both tiles (wave w -> o 16-slice) ----
    {
        int o = (w << 4) | m16;
        float bo = b_out[o];
        f32x4 acc0 = {0.f, 0.f, 0.f, 0.f};
        f32x4 acc1 = {0.f, 0.f, 0.f, 0.f};
#pragma unroll 8
        for (int ks = 0; ks < 64; ++ks) {
            int k = ks * 32 + quad * 8;
            f16x8 bfr = *(const f16x8*)(mtp + ((size_t)(ks * 4 + quad) * 256 + o) * 8);
            f16x8 af0 = *(const f16x8*)a_addr(A0, m16, k);
            f16x8 af1 = *(const f16x8*)a_addr(A1, m16, k);
            acc0 = __builtin_amdgcn_mfma_f32_16x16x32_f16(af0, bfr, acc0, 0, 0, 0);
            acc1 = __builtin_amdgcn_mfma_f32_16x16x32_f16(af1, bfr, acc1, 0, 0, 0);
        }
        float* drow = out + ((size_t)b * 256 + o) * 1024 + hw0;
        float4 r0 = {acc0[0] + bo, acc0[1] + bo, acc0[2] + bo, acc0[3] + bo};
        float4 r1 = {acc1[0] + bo, acc1[1] + bo, acc1[2] + bo, acc1[3] + bo};
        *(float4*)(drow + quad * 4)      = r0;   // tile0: px = quad*4+r
        *(float4*)(drow + 16 + quad * 4) = r1;   // tile1: px+16
    }
}

extern "C" void kernel_launch(void* const* d_in, const int* in_sizes, int n_in,
                              void* d_out, int out_size, void* d_ws, size_t ws_size,
                              hipStream_t stream) {
    (void)in_sizes; (void)n_in; (void)out_size; (void)ws_size;
    const int*   q     = (const int*)d_in[0];
    const float* c     = (const float*)d_in[1];
    const float* rms_w = (const float*)d_in[2];
    const float* emb   = (const float*)d_in[3];
    const float* w1    = (const float*)d_in[4];
    const float* b1    = (const float*)d_in[5];
    const float* w2    = (const float*)d_in[6];
    const float* b2    = (const float*)d_in[7];
    const float* w_kv  = (const float*)d_in[8];
    const float* w_out = (const float*)d_in[9];
    const float* b_out = (const float*)d_in[10];
    float* out = (float*)d_out;

    // ws layout: qkw [8b][8e][256c] f16 = 32 KiB at 0; mtp [256kc][256o][8] f16 = 1 MiB
    char* ws = (char*)d_ws;
    f16* qkw = (f16*)ws;                 // [0, 32768)
    f16* mtp = (f16*)(ws + 32768);       // [32768, +1 MiB)

    k_setup<<<65, 1024, 0, stream>>>(q, emb, w1, b1, w2, b2, w_kv, w_out, rms_w, qkw, mtp);
    k_attn <<<256, 1024, 0, stream>>>(c, qkw, mtp, b_out, out);
}

// Round 3
// 176.030 us; speedup vs baseline: 1.6232x; 1.6232x over previous
//
#include <hip/hip_runtime.h>

typedef _Float16 f16;
typedef _Float16 f16x4 __attribute__((ext_vector_type(4)));
typedef _Float16 f16x8 __attribute__((ext_vector_type(8)));
typedef float f32x4 __attribute__((ext_vector_type(4)));

// A[px][k]: 16 px rows x 2048 f16 (4096 B per row). 16-B chunks XOR-swizzled
// by px (4 bits): byte = px*4096 + ((k>>3)^(px&15))*16 + (k&7)*2.
static __device__ inline char* a_addr(char* Abase, int px, int k) {
    return Abase + px * 4096 + ((((k >> 3) ^ (px & 15)) << 4) | ((k & 7) << 1));
}

// ---------------------------------------------------------------------------
// k_setup (reverted to R0/R1 proven version): one launch, no internal deps.
// blocks 0..63:   (b,e): full query path redundantly
// blocks 64..319: M_e = Wv_e @ w_out_e, rw-folded -> mtp[kchunk][o][8] f16
// ---------------------------------------------------------------------------
__launch_bounds__(256)
__global__ void k_setup(const int* __restrict__ q, const float* __restrict__ emb,
                        const float* __restrict__ w1, const float* __restrict__ b1,
                        const float* __restrict__ w2, const float* __restrict__ b2,
                        const float* __restrict__ w_kv, const float* __restrict__ w_out,
                        const float* __restrict__ rms_w,
                        f16* __restrict__ qkw, f16* __restrict__ mtp) {
    int blk = blockIdx.x;
    int t = threadIdx.x;
    __shared__ float qe[256];
    __shared__ float x1L[512];
    __shared__ float ps[4][64];
    __shared__ float qhL[64];
    __shared__ float wv[64][8];

    if (blk < 64) {
        // ---- query-path role: (b, e) ----
        int b = blk >> 3, e = blk & 7;
        qe[t] = emb[(size_t)q[b] * 256 + t];
        __syncthreads();
        float a0 = b1[t], a1 = b1[t + 256];
#pragma unroll 4
        for (int c = 0; c < 256; ++c) {
            float qv = qe[c];
            a0 += qv * w1[c * 512 + t];
            a1 += qv * w1[c * 512 + t + 256];
        }
        x1L[t]       = a0 / (1.f + __expf(-a0));
        x1L[t + 256] = a1 / (1.f + __expf(-a1));
        __syncthreads();
        int d = t & 63, ks = t >> 6;
        float acc = 0.f;
#pragma unroll 4
        for (int k = ks * 128; k < ks * 128 + 128; ++k)
            acc += x1L[k] * w2[k * 512 + e * 64 + d];
        ps[ks][d] = acc;
        __syncthreads();
        if (t < 64)
            qhL[t] = b2[e * 64 + t] + ps[0][t] + ps[1][t] + ps[2][t] + ps[3][t];
        __syncthreads();
        const float* row = w_kv + (size_t)t * 1024 + e * 128;   // K-half of head e
        float a2 = 0.f;
#pragma unroll
        for (int dd = 0; dd < 64; dd += 4) {
            float4 wv4 = *(const float4*)(row + dd);
            a2 += qhL[dd] * wv4.x + qhL[dd + 1] * wv4.y + qhL[dd + 2] * wv4.z + qhL[dd + 3] * wv4.w;
        }
        qkw[(b * 8 + e) * 256 + t] = (f16)(a2 * rms_w[t]);
    } else {
        // ---- M role: (e, 8-c tile) ----
        int mb = blk - 64;
        int e = mb >> 5, c0 = (mb & 31) * 8;
        {
            int d = t & 63, cc = t >> 6;
            wv[d][cc]     = w_kv[(size_t)(c0 + cc) * 1024 + e * 128 + 64 + d];
            wv[d][cc + 4] = w_kv[(size_t)(c0 + cc + 4) * 1024 + e * 128 + 64 + d];
        }
        __syncthreads();
        int o = t;
        float acc[8];
#pragma unroll
        for (int c = 0; c < 8; ++c) acc[c] = 0.f;
#pragma unroll 4
        for (int d = 0; d < 64; ++d) {
            float wo = w_out[(size_t)(e * 64 + d) * 256 + o];
            float4 wa = *(const float4*)&wv[d][0];
            float4 wb = *(const float4*)&wv[d][4];
            acc[0] += wa.x * wo; acc[1] += wa.y * wo; acc[2] += wa.z * wo; acc[3] += wa.w * wo;
            acc[4] += wb.x * wo; acc[5] += wb.y * wo; acc[6] += wb.z * wo; acc[7] += wb.w * wo;
        }
        f16x8 ov;
#pragma unroll
        for (int c = 0; c < 8; ++c) ov[c] = (f16)(acc[c] * rms_w[c0 + c]);
        *(f16x8*)(mtp + ((size_t)((e * 256 + c0) >> 3) * 256 + o) * 8) = ov;
    }
}

// ---------------------------------------------------------------------------
// helpers for k_attn (operate on one 16-px tile in LDS buffer A)
// ---------------------------------------------------------------------------
static __device__ inline void dots_rinv(char* A, const f16* qkw_b,
                                        float (*dotsP)[8][16], float (*wred)[16],
                                        float (*rinvL)[9],
                                        int t, int w, int m16, int quad) {
    if (w < 8) {                       // dots via MFMA: wave w -> n = w
        int n = w;
        f32x4 d0 = {0.f, 0.f, 0.f, 0.f};
        const f16* qrow = qkw_b + (m16 & 7) * 256;
#pragma unroll
        for (int ks = 0; ks < 8; ++ks) {
            f16x8 a0 = *(const f16x8*)a_addr(A, m16, n * 256 + ks * 32 + quad * 8);
            f16x8 bq = *(const f16x8*)(qrow + ks * 32 + quad * 8);
            d0 = __builtin_amdgcn_mfma_f32_16x16x32_f16(a0, bq, d0, 0, 0, 0);
        }
        if (m16 < 8) {                 // D: col=m16=e, row=quad*4+r=px
#pragma unroll
            for (int r = 0; r < 4; ++r) dotsP[n][m16][quad * 4 + r] = d0[r];
        }
    } else if (w < 10) {               // rinv: 128 threads -> (px, n)
        int i = t - 512;
        int p = i & 15, n = i >> 4;
        float ss = wred[2 * n][p] + wred[2 * n + 1][p];
        rinvL[p][n] = rsqrtf(ss * (1.f / 256.f) + 1e-6f);
    }
}

static __device__ inline void blend(char* A, float (*dotsP)[8][16],
                                    float (*rinvL)[9], int t) {
    int bpx = t & 15;
    int cw = t >> 4;                   // 0..63, 4-channel window
    float rinv[8];
#pragma unroll
    for (int n = 0; n < 8; ++n) rinv[n] = rinvL[bpx][n];
    f16x4 cv[8];
#pragma unroll
    for (int n = 0; n < 8; ++n)
        cv[n] = *(const f16x4*)a_addr(A, bpx, n * 256 + cw * 4);
#pragma unroll
    for (int e = 0; e < 8; ++e) {
        float l[8];
#pragma unroll
        for (int n = 0; n < 8; ++n) l[n] = dotsP[n][e][bpx] * rinv[n] * 0.125f;
        float mx = l[0];
#pragma unroll
        for (int n = 1; n < 8; ++n) mx = fmaxf(mx, l[n]);
        float s = 0.f;
#pragma unroll
        for (int n = 0; n < 8; ++n) { l[n] = __expf(l[n] - mx); s += l[n]; }
        float inv = 1.f / s;
        f16x4 r = {};
#pragma unroll
        for (int n = 0; n < 8; ++n) {
            f16 an = (f16)(l[n] * inv * rinv[n]);
#pragma unroll
            for (int j = 0; j < 4; ++j) r[j] += cv[n][j] * an;   // v_pk_fma_f16
        }
        *(f16x4*)a_addr(A, bpx, e * 256 + cw * 4) = r;
    }
}

// ---------------------------------------------------------------------------
// k_attn v3: 1024 threads, TWO 16-px tiles per block, grid 256, 1 block/CU.
// Both tiles' global loads issued up-front (register-staged); tile1's flight
// hides under tile0's dots/blend. GEMMs fused: one mtp B-fragment feeds both
// tiles' MFMAs -> B L2-traffic halved (256 MiB total, ~7.8 us/CU floor).
// ---------------------------------------------------------------------------
__launch_bounds__(1024, 4)
__global__ void k_attn(const float* __restrict__ cin, const f16* __restrict__ qkw,
                       const f16* __restrict__ mtp, const float* __restrict__ b_out,
                       float* __restrict__ out) {
    int blk = blockIdx.x;
    int b = blk & 7;                  // XCD-local c[b] slab
    int hw0 = (blk >> 3) * 32;        // tile0 at hw0, tile1 at hw0+16
    int t = threadIdx.x;
    int lane = t & 63, w = t >> 6;    // w 0..15
    int m16 = lane & 15, quad = lane >> 4;

    __shared__ char A0[16 * 4096];    // 64 KiB swizzled f16 [16px][2048k]
    __shared__ char A1[16 * 4096];    // 64 KiB
    __shared__ float dotsP[8][8][16];
    __shared__ float wred[16][16];
    __shared__ float rinvL[16][9];

    // ---- issue BOTH tiles' loads; stage tile0 ----
    int px = m16;
    int cb = (w << 2) | quad;         // 0..63: rows cb*32..cb*32+31
    const float* src0 = cin + ((size_t)b * 2048 + (size_t)cb * 32) * 1024 + hw0 + px;
    const float* src1 = src0 + 16;

    float v0[32], v1[32];
#pragma unroll
    for (int j = 0; j < 32; ++j) v0[j] = src0[(size_t)j << 10];
    float ss0 = 0.f;
    {   // consume first 8 to keep VMEM FIFO <= 56 outstanding
        f16x8 h;
#pragma unroll
        for (int j = 0; j < 8; ++j) { float x = v0[j]; ss0 += x * x; h[j] = (f16)x; }
        *(f16x8*)a_addr(A0, px, cb * 32) = h;
    }
#pragma unroll
    for (int j = 0; j < 32; ++j) v1[j] = src1[(size_t)j << 10];
#pragma unroll
    for (int g = 1; g < 4; ++g) {
        f16x8 h;
#pragma unroll
        for (int j = 0; j < 8; ++j) { float x = v0[g * 8 + j]; ss0 += x * x; h[j] = (f16)x; }
        *(f16x8*)a_addr(A0, px, cb * 32 + g * 8) = h;
    }
    ss0 += __shfl_xor(ss0, 16);
    ss0 += __shfl_xor(ss0, 32);
    if (lane < 16) wred[w][lane] = ss0;
    __syncthreads();

    dots_rinv(A0, qkw + (size_t)b * 2048, dotsP, wred, rinvL, t, w, m16, quad);
    __syncthreads();
    blend(A0, dotsP, rinvL, t);
    __syncthreads();

    // ---- stage tile1 (v1 regs: flight was hidden under dots0/blend0) ----
    float ss1 = 0.f;
#pragma unroll
    for (int g = 0; g < 4; ++g) {
        f16x8 h;
#pragma unroll
        for (int j = 0; j < 8; ++j) { float x = v1[g * 8 + j]; ss1 += x * x; h[j] = (f16)x; }
        *(f16x8*)a_addr(A1, px, cb * 32 + g * 8) = h;
    }
    ss1 += __shfl_xor(ss1, 16);
    ss1 += __shfl_xor(ss1, 32);
    if (lane < 16) wred[w][lane] = ss1;
    __syncthreads();

    dots_rinv(A1, qkw + (size_t)b * 2048, dotsP, wred, rinvL, t, w, m16, quad);
    __syncthreads();
    blend(A1, dotsP, rinvL, t);
    __syncthreads();

    // ---- fused GEMM: one B-fragment -> both tiles (wave w -> o 16-slice) ----
    {
        int o = (w << 4) | m16;
        float bo = b_out[o];
        f32x4 acc0 = {0.f, 0.f, 0.f, 0.f};
        f32x4 acc1 = {0.f, 0.f, 0.f, 0.f};
#pragma unroll 8
        for (int ks = 0; ks < 64; ++ks) {
            int k = ks * 32 + quad * 8;
            f16x8 bfr = *(const f16x8*)(mtp + ((size_t)(ks * 4 + quad) * 256 + o) * 8);
            f16x8 af0 = *(const f16x8*)a_addr(A0, m16, k);
            f16x8 af1 = *(const f16x8*)a_addr(A1, m16, k);
            acc0 = __builtin_amdgcn_mfma_f32_16x16x32_f16(af0, bfr, acc0, 0, 0, 0);
            acc1 = __builtin_amdgcn_mfma_f32_16x16x32_f16(af1, bfr, acc1, 0, 0, 0);
        }
        float* drow = out + ((size_t)b * 256 + o) * 1024 + hw0;
        float4 r0 = {acc0[0] + bo, acc0[1] + bo, acc0[2] + bo, acc0[3] + bo};
        float4 r1 = {acc1[0] + bo, acc1[1] + bo, acc1[2] + bo, acc1[3] + bo};
        *(float4*)(drow + quad * 4)      = r0;   // tile0: px = quad*4+r
        *(float4*)(drow + 16 + quad * 4) = r1;   // tile1: px+16
    }
}

extern "C" void kernel_launch(void* const* d_in, const int* in_sizes, int n_in,
                              void* d_out, int out_size, void* d_ws, size_t ws_size,
                              hipStream_t stream) {
    (void)in_sizes; (void)n_in; (void)out_size; (void)ws_size;
    const int*   q     = (const int*)d_in[0];
    const float* c     = (const float*)d_in[1];
    const float* rms_w = (const float*)d_in[2];
    const float* emb   = (const float*)d_in[3];
    const float* w1    = (const float*)d_in[4];
    const float* b1    = (const float*)d_in[5];
    const float* w2    = (const float*)d_in[6];
    const float* b2    = (const float*)d_in[7];
    const float* w_kv  = (const float*)d_in[8];
    const float* w_out = (const float*)d_in[9];
    const float* b_out = (const float*)d_in[10];
    float* out = (float*)d_out;

    // ws layout: qkw [8b][8e][256c] f16 = 32 KiB at 0; mtp [256kc][256o][8] f16 = 1 MiB
    char* ws = (char*)d_ws;
    f16* qkw = (f16*)ws;                 // [0, 32768)
    f16* mtp = (f16*)(ws + 32768);       // [32768, +1 MiB)

    k_setup<<<320, 256, 0, stream>>>(q, emb, w1, b1, w2, b2, w_kv, w_out, rms_w, qkw, mtp);
    k_attn <<<256, 1024, 0, stream>>>(c, qkw, mtp, b_out, out);
}

// Round 4
// 171.783 us; speedup vs baseline: 1.6634x; 1.0247x over previous
//
#include <hip/hip_runtime.h>

typedef _Float16 f16;
typedef _Float16 f16x4 __attribute__((ext_vector_type(4)));
typedef _Float16 f16x8 __attribute__((ext_vector_type(8)));
typedef float f32x4 __attribute__((ext_vector_type(4)));

// A[px][k]: 32 px rows x 2048 f16 (4096 B per row). 16-B chunks XOR-swizzled
// by px (4 bits): byte = px*4096 + ((k>>3)^(px&15))*16 + (k&7)*2.
static __device__ inline char* a_addr(char* Abase, int px, int k) {
    return Abase + px * 4096 + ((((k >> 3) ^ (px & 15)) << 4) | ((k & 7) << 1));
}

// ---------------------------------------------------------------------------
// k_setup v4: grid 72 x 1024.
// blocks 0..7:  query path for b=blk (16 waves/CU for latency hiding, no
//               redundant recompute; matmuls split over 2 thread-halves + LDS)
// blocks 8..71: M role, 4 subtiles each (R0 inner loop verbatim, no big
//               per-thread arrays): M_e = Wv_e @ w_out_e -> mtp
// ---------------------------------------------------------------------------
__launch_bounds__(1024)
__global__ void k_setup(const int* __restrict__ q, const float* __restrict__ emb,
                        const float* __restrict__ w1, const float* __restrict__ b1,
                        const float* __restrict__ w2, const float* __restrict__ b2,
                        const float* __restrict__ w_kv, const float* __restrict__ w_out,
                        const float* __restrict__ rms_w,
                        f16* __restrict__ qkw, f16* __restrict__ mtp) {
    int blk = blockIdx.x;
    int t = threadIdx.x;

    if (blk < 8) {
        // ---- query path: b = blk ----
        int b = blk;
        __shared__ float qe[256];
        __shared__ float x1[512];
        __shared__ float qh[512];
        __shared__ float psA[1024];
        __shared__ float psB[1024];

        if (t < 256) qe[t] = emb[(size_t)q[b] * 256 + t];
        __syncthreads();

        {   // x1 = silu(qe @ w1 + b1); thread = (h, c-half)
            int h = t & 511, half = t >> 9;
            float acc = half ? 0.f : b1[h];
            int c0 = half * 128;
#pragma unroll 8
            for (int c = c0; c < c0 + 128; ++c)
                acc += qe[c] * w1[(size_t)c * 512 + h];
            psA[half * 512 + h] = acc;
        }
        __syncthreads();
        if (t < 512) {
            float a = psA[t] + psA[512 + t];
            x1[t] = a / (1.f + __expf(-a));
        }
        __syncthreads();

        {   // qh = x1 @ w2 + b2; thread = (o, k-half)
            int o = t & 511, half = t >> 9;
            float acc = half ? 0.f : b2[o];
            int k0 = half * 256;
#pragma unroll 8
            for (int k = k0; k < k0 + 256; ++k)
                acc += x1[k] * w2[(size_t)k * 512 + o];
            psB[half * 512 + o] = acc;
        }
        __syncthreads();
        if (t < 512) qh[t] = psB[t] + psB[512 + t];
        __syncthreads();

        {   // qkw[b,e,c] = rms_w[c] * sum_d qh[e*64+d] * w_kv[c][e*128+d]
            int c = t & 255, g = t >> 8;          // g 0..3 -> e = 2g, 2g+1
            float rw = rms_w[c];
#pragma unroll
            for (int ee = 0; ee < 2; ++ee) {
                int e = g * 2 + ee;
                const float* col = w_kv + (size_t)c * 1024 + e * 128;  // K-half
                float acc = 0.f;
#pragma unroll
                for (int dq = 0; dq < 16; ++dq) {
                    float4 wv4 = *(const float4*)(col + dq * 4);
                    const float* qb = &qh[e * 64 + dq * 4];
                    acc += wv4.x * qb[0] + wv4.y * qb[1]
                         + wv4.z * qb[2] + wv4.w * qb[3];
                }
                qkw[((size_t)b * 8 + e) * 256 + c] = (f16)(acc * rw);
            }
        }
    } else {
        // ---- M role: 4 subtiles of (e, 8-c tile); inner loop = R0 verbatim ----
        __shared__ float wv[4][64][8];
        int sub = t >> 8, st = t & 255;
        int mb = (blk - 8) * 4 + sub;
        int e = mb >> 5, c0 = (mb & 31) * 8;
        {
            int d = st & 63, cc = st >> 6;
            wv[sub][d][cc]     = w_kv[(size_t)(c0 + cc) * 1024 + e * 128 + 64 + d];
            wv[sub][d][cc + 4] = w_kv[(size_t)(c0 + cc + 4) * 1024 + e * 128 + 64 + d];
        }
        __syncthreads();
        int o = st;
        float acc[8];
#pragma unroll
        for (int c = 0; c < 8; ++c) acc[c] = 0.f;
#pragma unroll 4
        for (int d = 0; d < 64; ++d) {
            float wo = w_out[(size_t)(e * 64 + d) * 256 + o];
            float4 wa = *(const float4*)&wv[sub][d][0];
            float4 wb = *(const float4*)&wv[sub][d][4];
            acc[0] += wa.x * wo; acc[1] += wa.y * wo; acc[2] += wa.z * wo; acc[3] += wa.w * wo;
            acc[4] += wb.x * wo; acc[5] += wb.y * wo; acc[6] += wb.z * wo; acc[7] += wb.w * wo;
        }
        f16x8 ov;
#pragma unroll
        for (int c = 0; c < 8; ++c) ov[c] = (f16)(acc[c] * rms_w[c0 + c]);
        *(f16x8*)(mtp + ((size_t)((e * 256 + c0) >> 3) * 256 + o) * 8) = ov;
    }
}

// ---------------------------------------------------------------------------
// k_attn v4: R0's proven 32-px structure; blend's 64x-redundant softmax moved
// to a one-shot attn-compute phase (256 threads) writing packed f16x8 attn
// weights into LDS (aliased onto the dead wred buffer -> no extra LDS).
// phases: [load + sumsq] -> [rinv(t<256) + dots MFMA] -> [pb preload issue;
// attn-compute(t<256)] -> [cheap blend] -> [GEMM] -> store.
// ---------------------------------------------------------------------------
__launch_bounds__(1024, 4)
__global__ void k_attn(const float* __restrict__ cin, const f16* __restrict__ qkw,
                       const f16* __restrict__ mtp, const float* __restrict__ b_out,
                       float* __restrict__ out) {
    int blk = blockIdx.x;
    int b = blk & 7;
    int hw0 = (blk >> 3) * 32;
    int t = threadIdx.x;
    int lane = t & 63, w = t >> 6;        // w 0..15
    int m16 = lane & 15, quad = lane >> 4;
    int half = lane >> 5;                 // 0/1

    __shared__ char A[32 * 4096];         // 131072 B, swizzled f16 [32px][2048k]
    __shared__ float dotsP[8][8][32];     //   8192 B [n][e][px]
    __shared__ char pool[16384];          // wred f32[16][8][32] -> attn f16[8][32][8]
    __shared__ float rinvL[32][8];        //   1024 B

    float* wredF = (float*)pool;          // wredF[w*256 + g*32 + px]
    f16*   attnH = (f16*)pool;            // attnH[e*256 + px*8 + n]

    // ---- load raw c -> A (f16, swizzled): thread = (px, 8-ch block cb) ----
    int px = lane & 31;
    int cb = w + half * 16;               // halves 16 apart -> 2-way stores
    const float* cbase = cin + ((size_t)b * 8 * 256) * 1024 + hw0 + px;
#pragma unroll
    for (int g = 0; g < 8; g += 2) {      // g-pair: 16 loads in flight
        const float* s0 = cbase + ((size_t)(g * 256 + cb * 8) << 10);
        const float* s1 = cbase + ((size_t)((g + 1) * 256 + cb * 8) << 10);
        float v0[8], v1[8];
#pragma unroll
        for (int j = 0; j < 8; ++j) v0[j] = s0[(size_t)j << 10];
#pragma unroll
        for (int j = 0; j < 8; ++j) v1[j] = s1[(size_t)j << 10];
        float sa = 0.f, sb = 0.f;
        f16x8 h0, h1;
#pragma unroll
        for (int j = 0; j < 8; ++j) { sa += v0[j] * v0[j]; h0[j] = (f16)v0[j]; }
#pragma unroll
        for (int j = 0; j < 8; ++j) { sb += v1[j] * v1[j]; h1[j] = (f16)v1[j]; }
        *(f16x8*)a_addr(A, px, g * 256 + cb * 8)       = h0;
        *(f16x8*)a_addr(A, px, (g + 1) * 256 + cb * 8) = h1;
        sa += __shfl_xor(sa, 32);         // combine the two cb halves (same px)
        sb += __shfl_xor(sb, 32);
        if (lane < 32) {
            wredF[w * 256 + g * 32 + px]       = sa;
            wredF[w * 256 + (g + 1) * 32 + px] = sb;
        }
    }
    __syncthreads();

    // ---- rinv (t<256) + dots via MFMA (wave w -> n=w&7, px-half=w>>3) ----
    if (t < 256) {
        int p = t >> 3, n = t & 7;
        float ss = 0.f;
#pragma unroll
        for (int ww = 0; ww < 16; ++ww) ss += wredF[ww * 256 + n * 32 + p];
        rinvL[p][n] = rsqrtf(ss * (1.f / 256.f) + 1e-6f);
    }
    {
        int n = w & 7, pxh = w >> 3;
        f32x4 d0 = {0.f, 0.f, 0.f, 0.f};
        const f16* qrow = qkw + (size_t)b * 2048 + (m16 & 7) * 256;
#pragma unroll
        for (int ks = 0; ks < 8; ++ks) {
            f16x8 a0  = *(const f16x8*)a_addr(A, pxh * 16 + m16, n * 256 + ks * 32 + quad * 8);
            f16x8 bfr = *(const f16x8*)(qrow + ks * 32 + quad * 8);
            d0 = __builtin_amdgcn_mfma_f32_16x16x32_f16(a0, bfr, d0, 0, 0, 0);
        }
        if (m16 < 8) {   // D: col=m16=e, row=quad*4+r
#pragma unroll
            for (int r = 0; r < 4; ++r) dotsP[n][m16][pxh * 16 + quad * 4 + r] = d0[r];
        }
    }
    __syncthreads();

    // ---- GEMM B-frag preload (ks 0..7), in flight across attn+blend ----
    int o = w * 16 + m16;
    f16x8 pb[8];
#pragma unroll
    for (int ks = 0; ks < 8; ++ks)
        pb[ks] = *(const f16x8*)(mtp + ((size_t)(ks * 4 + quad) * 256 + o) * 8);

    // ---- attn-compute: one softmax per (px,e), packed f16x8 over n ----
    if (t < 256) {
        int e = t >> 5, p = t & 31;       // lanes p-consecutive
        float rv[8], l[8];
#pragma unroll
        for (int n = 0; n < 8; ++n) rv[n] = rinvL[p][n];
#pragma unroll
        for (int n = 0; n < 8; ++n) l[n] = dotsP[n][e][p] * rv[n] * 0.125f;
        float mx = l[0];
#pragma unroll
        for (int n = 1; n < 8; ++n) mx = fmaxf(mx, l[n]);
        float s = 0.f;
#pragma unroll
        for (int n = 0; n < 8; ++n) { l[n] = __expf(l[n] - mx); s += l[n]; }
        float inv = 1.f / s;
        f16x8 av;
#pragma unroll
        for (int n = 0; n < 8; ++n) av[n] = (f16)(l[n] * inv * rv[n]);
        *(f16x8*)(attnH + e * 256 + p * 8) = av;
    }
    __syncthreads();

    // ---- cheap blend (in place over A): no per-window softmax ----
    {
        int bpx = lane & 31;
        int c0 = (w + half * 16) * 8;     // halves 16 windows apart -> 2-way
        f16x8 cv[8];
#pragma unroll
        for (int n = 0; n < 8; ++n)
            cv[n] = *(const f16x8*)a_addr(A, bpx, n * 256 + c0);
#pragma unroll
        for (int e = 0; e < 8; ++e) {
            f16x8 av = *(const f16x8*)(attnH + e * 256 + bpx * 8);
            f16x8 r = {};
#pragma unroll
            for (int n = 0; n < 8; ++n) {
                f16 an = av[n];
#pragma unroll
                for (int j = 0; j < 8; ++j) r[j] += cv[n][j] * an;   // v_pk_fma_f16
            }
            *(f16x8*)a_addr(A, bpx, e * 256 + c0) = r;
        }
    }
    __syncthreads();

    // ---- GEMM: out[32p][256o] = A[32][2048] @ M  (wave w -> o 16-slice) ----
    {
        f32x4 acc0 = {0.f, 0.f, 0.f, 0.f};
        f32x4 acc1 = {0.f, 0.f, 0.f, 0.f};
#pragma unroll
        for (int ks = 0; ks < 8; ++ks) {   // preloaded B
            int k = ks * 32 + quad * 8;
            f16x8 af0 = *(const f16x8*)a_addr(A, m16, k);
            f16x8 af1 = *(const f16x8*)a_addr(A, m16 + 16, k);
            acc0 = __builtin_amdgcn_mfma_f32_16x16x32_f16(af0, pb[ks], acc0, 0, 0, 0);
            acc1 = __builtin_amdgcn_mfma_f32_16x16x32_f16(af1, pb[ks], acc1, 0, 0, 0);
        }
#pragma unroll 8
        for (int ks = 8; ks < 64; ++ks) {
            int k = (ks >> 3) * 256 + (ks & 7) * 32 + quad * 8;
            int kchunk = k >> 3;
            f16x8 bfr = *(const f16x8*)(mtp + ((size_t)kchunk * 256 + o) * 8);
            f16x8 af0 = *(const f16x8*)a_addr(A, m16, k);
            f16x8 af1 = *(const f16x8*)a_addr(A, m16 + 16, k);
            acc0 = __builtin_amdgcn_mfma_f32_16x16x32_f16(af0, bfr, acc0, 0, 0, 0);
            acc1 = __builtin_amdgcn_mfma_f32_16x16x32_f16(af1, bfr, acc1, 0, 0, 0);
        }
        float bo = b_out[o];
        float* drow = out + ((size_t)b * 256 + o) * 1024 + hw0;
        float4 v0 = {acc0[0] + bo, acc0[1] + bo, acc0[2] + bo, acc0[3] + bo};
        float4 v1 = {acc1[0] + bo, acc1[1] + bo, acc1[2] + bo, acc1[3] + bo};
        *(float4*)(drow + quad * 4)      = v0;   // px 0..15 half
        *(float4*)(drow + 16 + quad * 4) = v1;   // px 16..31 half
    }
}

extern "C" void kernel_launch(void* const* d_in, const int* in_sizes, int n_in,
                              void* d_out, int out_size, void* d_ws, size_t ws_size,
                              hipStream_t stream) {
    (void)in_sizes; (void)n_in; (void)out_size; (void)ws_size;
    const int*   q     = (const int*)d_in[0];
    const float* c     = (const float*)d_in[1];
    const float* rms_w = (const float*)d_in[2];
    const float* emb   = (const float*)d_in[3];
    const float* w1    = (const float*)d_in[4];
    const float* b1    = (const float*)d_in[5];
    const float* w2    = (const float*)d_in[6];
    const float* b2    = (const float*)d_in[7];
    const float* w_kv  = (const float*)d_in[8];
    const float* w_out = (const float*)d_in[9];
    const float* b_out = (const float*)d_in[10];
    float* out = (float*)d_out;

    // ws layout: qkw [8b][8e][256c] f16 = 32 KiB at 0; mtp [256kc][256o][8] f16 = 1 MiB
    char* ws = (char*)d_ws;
    f16* qkw = (f16*)ws;                 // [0, 32768)
    f16* mtp = (f16*)(ws + 32768);       // [32768, +1 MiB)

    k_setup<<<72, 1024, 0, stream>>>(q, emb, w1, b1, w2, b2, w_kv, w_out, rms_w, qkw, mtp);
    k_attn <<<256, 1024, 0, stream>>>(c, qkw, mtp, b_out, out);
}